// Round 2
// baseline (219.176 us; speedup 1.0000x reference)
//
#include <hip/hip_runtime.h>
#include <hip/hip_bf16.h>
#include <cmath>

typedef unsigned short u16;
typedef __attribute__((ext_vector_type(8))) short s8v;   // 8 x bf16 bits
typedef __attribute__((ext_vector_type(4))) float f4v;

#define MFMA(a,b,c) __builtin_amdgcn_mfma_f32_16x16x32_bf16((a),(b),(c),0,0,0)

__device__ __forceinline__ u16 f2bf(float f) {
    union { float f; unsigned i; } x; x.f = f;
    unsigned r = x.i + 0x7FFFu + ((x.i >> 16) & 1u);
    return (u16)(r >> 16);
}

// ---------------------------------------------------------------------------
// Kernel 1: fused QKV projection (f32 in -> bf16 MFMA -> bf16 QH/KH/VH).
// A[m][k]: m = b*2048 + t (t = v*256 + hw), k = c_in.  From q (nt<4) or kv.
// B[k][n]: Wq or Wkv.  Outputs QH/KH/VH in [b][h][T][d] (bf16).
// ---------------------------------------------------------------------------
__global__ __launch_bounds__(256)
void qkv_proj(const float* __restrict__ q, const float* __restrict__ kv,
              const float* __restrict__ Wq, const float* __restrict__ bq,
              const float* __restrict__ Wkv, const float* __restrict__ bkv,
              u16* __restrict__ QH, u16* __restrict__ KH, u16* __restrict__ VH)
{
    __shared__ u16 Al[128][40];   // [m][k], pad to 40
    __shared__ u16 Bl[128][40];   // [n][k]

    const int bid = blockIdx.x;
    const int mt = bid / 12, nt = bid - mt * 12;
    const int m0 = mt << 7, n0 = nt << 7;

    const int tid  = threadIdx.x;
    const int lane = tid & 63;
    const int w    = tid >> 6;
    const int wr = (w >> 1) * 64, wc = (w & 1) * 64;
    const int cl = lane & 15, rl = lane >> 4;

    const int bb  = m0 >> 11;
    const int t0  = m0 & 2047;
    const int vv  = t0 >> 8;
    const int hw0 = t0 & 255;

    const float* Abase = ((nt < 4) ? q : kv) + (size_t)(vv * 4 + bb) * 131072 + hw0;

    const float* W; const float* bias; int NW, wn0, dn0; u16* dst;
    if (nt < 4)      { W = Wq;  bias = bq;  NW = 512;  wn0 = n0;       dn0 = n0;        dst = QH; }
    else if (nt < 8) { W = Wkv; bias = bkv; NW = 1024; wn0 = n0 - 512; dn0 = n0 - 512;  dst = KH; }
    else             { W = Wkv; bias = bkv; NW = 1024; wn0 = n0 - 512; dn0 = n0 - 1024; dst = VH; }

    f4v acc[4][4] = {};

    const int lk = tid >> 3;          // k within tile: 0..31
    const int lg = (tid & 7) * 16;    // m/n group base: 0,16,...,112

    for (int k0 = 0; k0 < 512; k0 += 32) {
        {   // A tile: f32 global contiguous along m (hw), cvt+transpose-on-write
            const float* g = Abase + (size_t)(k0 + lk) * 256 + lg;
            #pragma unroll
            for (int u = 0; u < 4; ++u) {
                f4v v = *reinterpret_cast<const f4v*>(g + u * 4);
                #pragma unroll
                for (int j = 0; j < 4; ++j) Al[lg + u * 4 + j][lk] = f2bf(v[j]);
            }
        }
        {   // B tile: f32 global contiguous along n, cvt+transpose-on-write
            const float* g = W + (size_t)(k0 + lk) * NW + wn0 + lg;
            #pragma unroll
            for (int u = 0; u < 4; ++u) {
                f4v v = *reinterpret_cast<const f4v*>(g + u * 4);
                #pragma unroll
                for (int j = 0; j < 4; ++j) Bl[lg + u * 4 + j][lk] = f2bf(v[j]);
            }
        }
        __syncthreads();
        s8v af[4], bf[4];
        #pragma unroll
        for (int mi = 0; mi < 4; ++mi)
            af[mi] = *reinterpret_cast<const s8v*>(&Al[wr + mi * 16 + cl][rl * 8]);
        #pragma unroll
        for (int ni = 0; ni < 4; ++ni)
            bf[ni] = *reinterpret_cast<const s8v*>(&Bl[wc + ni * 16 + cl][rl * 8]);
        #pragma unroll
        for (int mi = 0; mi < 4; ++mi)
            #pragma unroll
            for (int ni = 0; ni < 4; ++ni)
                acc[mi][ni] = MFMA(af[mi], bf[ni], acc[mi][ni]);
        __syncthreads();
    }

    #pragma unroll
    for (int ni = 0; ni < 4; ++ni) {
        const int nl   = wc + ni * 16 + cl;
        const float bv = bias[wn0 + nl];
        const int cout = dn0 + nl;
        const int hh = cout >> 6, dd = cout & 63;
        const size_t obase = ((size_t)(bb * 8 + hh) * 2048) * 64 + dd;
        #pragma unroll
        for (int mi = 0; mi < 4; ++mi)
            #pragma unroll
            for (int r = 0; r < 4; ++r) {
                const int m = m0 + wr + mi * 16 + rl * 4 + r;
                const int t = m & 2047;
                dst[obase + (size_t)t * 64] = f2bf(acc[mi][ni][r] + bv);
            }
    }
}

// ---------------------------------------------------------------------------
// Kernel 2: block-causal flash attention. WG = (b,h,q-tile of 128 rows),
// heaviest q-tiles first. 4 waves x 32 q-rows. scale folded into exp2.
// ---------------------------------------------------------------------------
__global__ __launch_bounds__(256)
void attn(const u16* __restrict__ QH, const u16* __restrict__ KH,
          const u16* __restrict__ VH, u16* __restrict__ YH)
{
    __shared__ u16 Vl[64][136];    // V^T tile: [d][key]
    __shared__ u16 Pl[128][136];   // per-wave P: rows [w*32, w*32+32)

    const int wg = blockIdx.x;
    const int qt = 15 - (wg >> 5);        // heavy tiles first
    const int bh = wg & 31;
    const int b = bh >> 3, h = bh & 7;
    const int tid = threadIdx.x, lane = tid & 63, w = tid >> 6;
    const int cl = lane & 15, rl = lane >> 4;
    const int nkt = ((qt >> 1) + 1) * 2;  // key tiles of 128 (block-causal)

    const u16* Qb = QH + (size_t)bh * 131072;
    const u16* Kb = KH + (size_t)bh * 131072;
    const u16* Vb = VH + (size_t)bh * 131072;

    const int qrow0 = qt * 128 + w * 32;

    s8v qf[2][2];
    #pragma unroll
    for (int mi = 0; mi < 2; ++mi)
        #pragma unroll
        for (int kf = 0; kf < 2; ++kf)
            qf[mi][kf] = *reinterpret_cast<const s8v*>(
                Qb + (size_t)(qrow0 + mi * 16 + cl) * 64 + kf * 32 + rl * 8);

    f4v o[2][4] = {};
    float mrun[8], lrun[8];
    #pragma unroll
    for (int i = 0; i < 8; ++i) { mrun[i] = -1e30f; lrun[i] = 0.f; }

    const float C = 0.125f * 1.44269504f;   // 1/sqrt(64) * log2(e)

    for (int kt = 0; kt < nkt; ++kt) {
        const int kb0 = kt * 128;
        __syncthreads();                    // prev-iter PV reads of Vl done
        {   // stage V^T: [key][d] global -> Vl[d][key]
            const int key = tid >> 1, dh = (tid & 1) * 32;
            const u16* g = Vb + (size_t)(kb0 + key) * 64 + dh;
            s8v v0 = *reinterpret_cast<const s8v*>(g);
            s8v v1 = *reinterpret_cast<const s8v*>(g + 8);
            s8v v2 = *reinterpret_cast<const s8v*>(g + 16);
            s8v v3 = *reinterpret_cast<const s8v*>(g + 24);
            #pragma unroll
            for (int j = 0; j < 8; ++j) Vl[dh + j][key]      = (u16)v0[j];
            #pragma unroll
            for (int j = 0; j < 8; ++j) Vl[dh + 8 + j][key]  = (u16)v1[j];
            #pragma unroll
            for (int j = 0; j < 8; ++j) Vl[dh + 16 + j][key] = (u16)v2[j];
            #pragma unroll
            for (int j = 0; j < 8; ++j) Vl[dh + 24 + j][key] = (u16)v3[j];
        }
        __syncthreads();

        // S = Q K^T  (K^T B-fragments straight from global; L2-resident)
        f4v sc[2][8] = {};
        #pragma unroll
        for (int ni = 0; ni < 8; ++ni)
            #pragma unroll
            for (int kf = 0; kf < 2; ++kf) {
                s8v kfr = *reinterpret_cast<const s8v*>(
                    Kb + (size_t)(kb0 + ni * 16 + cl) * 64 + kf * 32 + rl * 8);
                sc[0][ni] = MFMA(qf[0][kf], kfr, sc[0][ni]);
                sc[1][ni] = MFMA(qf[1][kf], kfr, sc[1][ni]);
            }

        // online softmax in D-layout; row stats shared across 16-lane groups
        #pragma unroll
        for (int mi = 0; mi < 2; ++mi)
            #pragma unroll
            for (int r = 0; r < 4; ++r) {
                float rm = sc[mi][0][r];
                #pragma unroll
                for (int ni = 1; ni < 8; ++ni) rm = fmaxf(rm, sc[mi][ni][r]);
                rm = fmaxf(rm, __shfl_xor(rm, 1));
                rm = fmaxf(rm, __shfl_xor(rm, 2));
                rm = fmaxf(rm, __shfl_xor(rm, 4));
                rm = fmaxf(rm, __shfl_xor(rm, 8));
                const int idx = mi * 4 + r;
                const float mn = fmaxf(mrun[idx], rm);
                const float alpha = exp2f((mrun[idx] - mn) * C);
                mrun[idx] = mn;
                float rs = 0.f;
                #pragma unroll
                for (int ni = 0; ni < 8; ++ni) {
                    const float p = exp2f((sc[mi][ni][r] - mn) * C);
                    Pl[w * 32 + mi * 16 + rl * 4 + r][ni * 16 + cl] = f2bf(p);
                    rs += p;
                }
                rs += __shfl_xor(rs, 1);
                rs += __shfl_xor(rs, 2);
                rs += __shfl_xor(rs, 4);
                rs += __shfl_xor(rs, 8);
                lrun[idx] = lrun[idx] * alpha + rs;
                #pragma unroll
                for (int di = 0; di < 4; ++di) o[mi][di][r] *= alpha;
            }

        // PV: P (A-frags from wave-local LDS) x V^T (B-frags from Vl)
        #pragma unroll
        for (int kfr = 0; kfr < 4; ++kfr) {
            s8v pf0 = *reinterpret_cast<const s8v*>(&Pl[w * 32 + cl][kfr * 32 + rl * 8]);
            s8v pf1 = *reinterpret_cast<const s8v*>(&Pl[w * 32 + 16 + cl][kfr * 32 + rl * 8]);
            #pragma unroll
            for (int di = 0; di < 4; ++di) {
                s8v vf = *reinterpret_cast<const s8v*>(&Vl[di * 16 + cl][kfr * 32 + rl * 8]);
                o[0][di] = MFMA(pf0, vf, o[0][di]);
                o[1][di] = MFMA(pf1, vf, o[1][di]);
            }
        }
    }

    // normalize and store Y in [b][t][c] (c = h*64 + d), bf16
    #pragma unroll
    for (int mi = 0; mi < 2; ++mi)
        #pragma unroll
        for (int r = 0; r < 4; ++r) {
            const float inv = 1.f / lrun[mi * 4 + r];
            const int t = qrow0 + mi * 16 + rl * 4 + r;
            #pragma unroll
            for (int di = 0; di < 4; ++di) {
                const int c = h * 64 + di * 16 + cl;
                YH[((size_t)b * 2048 + t) * 512 + c] = f2bf(o[mi][di][r] * inv);
            }
        }
}

// ---------------------------------------------------------------------------
// Kernel 3: output projection, computed transposed: C'[c][tok] = Wp^T . Y^T,
// so f32 stores are contiguous along hw of the v b c h w output layout.
// ---------------------------------------------------------------------------
__global__ __launch_bounds__(256)
void out_proj(const u16* __restrict__ YH, const float* __restrict__ Wp,
              const float* __restrict__ bp, float* __restrict__ out)
{
    __shared__ u16 Al[128][40];   // Wp^T tile: [cout][cin]
    __shared__ u16 Bl[128][40];   // Y tile: [token][cin] (linear copy)

    const int bid = blockIdx.x;
    const int ct = bid >> 6;      // cout tile 0..3
    const int mt = bid & 63;      // token tile 0..63
    const int c0 = ct << 7, m0 = mt << 7;

    const int tid = threadIdx.x, lane = tid & 63, w = tid >> 6;
    const int wr = (w >> 1) * 64, wc = (w & 1) * 64;
    const int cl = lane & 15, rl = lane >> 4;

    f4v acc[4][4] = {};

    const int lk = tid >> 3;
    const int lg = (tid & 7) * 16;
    const int br = tid >> 2;            // 0..63
    const int bq4 = (tid & 3) * 8;

    for (int k0 = 0; k0 < 512; k0 += 32) {
        {   // A: Wp[k][c] f32 -> Al[c][k] (cvt + transpose-on-write)
            const float* g = Wp + (size_t)(k0 + lk) * 512 + c0 + lg;
            #pragma unroll
            for (int u = 0; u < 4; ++u) {
                f4v v = *reinterpret_cast<const f4v*>(g + u * 4);
                #pragma unroll
                for (int j = 0; j < 4; ++j) Al[lg + u * 4 + j][lk] = f2bf(v[j]);
            }
        }
        #pragma unroll
        for (int it = 0; it < 2; ++it) {  // B: Y rows (bf16), linear ds_write_b128
            const int row = br + it * 64;
            s8v v = *reinterpret_cast<const s8v*>(YH + (size_t)(m0 + row) * 512 + k0 + bq4);
            *reinterpret_cast<s8v*>(&Bl[row][bq4]) = v;
        }
        __syncthreads();
        s8v af[4], bfr[4];
        #pragma unroll
        for (int mi = 0; mi < 4; ++mi)
            af[mi] = *reinterpret_cast<const s8v*>(&Al[wr + mi * 16 + cl][rl * 8]);
        #pragma unroll
        for (int ni = 0; ni < 4; ++ni)
            bfr[ni] = *reinterpret_cast<const s8v*>(&Bl[wc + ni * 16 + cl][rl * 8]);
        #pragma unroll
        for (int mi = 0; mi < 4; ++mi)
            #pragma unroll
            for (int ni = 0; ni < 4; ++ni)
                acc[mi][ni] = MFMA(af[mi], bfr[ni], acc[mi][ni]);
        __syncthreads();
    }

    #pragma unroll
    for (int mi = 0; mi < 4; ++mi)
        #pragma unroll
        for (int r = 0; r < 4; ++r) {
            const int c = c0 + wr + mi * 16 + rl * 4 + r;   // D row = cout
            const float bv = bp[c];
            #pragma unroll
            for (int ni = 0; ni < 4; ++ni) {
                const int tok = m0 + wc + ni * 16 + cl;     // D col = token
                const int bb = tok >> 11, t = tok & 2047;
                const int vv = t >> 8, hw = t & 255;
                out[(size_t)(vv * 4 + bb) * 131072 + (size_t)c * 256 + hw] =
                    acc[mi][ni][r] + bv;
            }
        }
}

// ---------------------------------------------------------------------------
extern "C" void kernel_launch(void* const* d_in, const int* in_sizes, int n_in,
                              void* d_out, int out_size, void* d_ws, size_t ws_size,
                              hipStream_t stream)
{
    const float* q   = (const float*)d_in[0];
    const float* kv  = (const float*)d_in[1];
    const float* Wq  = (const float*)d_in[2];
    const float* bq  = (const float*)d_in[3];
    const float* Wkv = (const float*)d_in[4];
    const float* bkv = (const float*)d_in[5];
    const float* Wp  = (const float*)d_in[6];
    const float* bp  = (const float*)d_in[7];
    float* out = (float*)d_out;

    u16* ws = (u16*)d_ws;
    u16* QH = ws;                    // [4][8][2048][64] bf16 = 8 MB
    u16* KH = QH + 4194304;
    u16* VH = KH + 4194304;
    u16* YH = VH + 4194304;          // [4][2048][512] bf16 = 8 MB

    hipLaunchKernelGGL(qkv_proj, dim3(768), dim3(256), 0, stream,
                       q, kv, Wq, bq, Wkv, bkv, QH, KH, VH);
    hipLaunchKernelGGL(attn, dim3(512), dim3(256), 0, stream, QH, KH, VH, YH);
    hipLaunchKernelGGL(out_proj, dim3(256), dim3(256), 0, stream, YH, Wp, bp, out);
}